// Round 3
// baseline (163.973 us; speedup 1.0000x reference)
//
#include <hip/hip_runtime.h>

#define MAX_FTS 30
#define HALF 256
#define ROWLEN 257

typedef __attribute__((ext_vector_type(2))) _Float16 f16x2;
typedef __attribute__((ext_vector_type(4))) _Float16 f16x4;
typedef __attribute__((ext_vector_type(8))) _Float16 f16x8;
typedef __attribute__((ext_vector_type(4))) float    f32x4;

// ---------------------------------------------------------------------------
// Pass 0: ft_w (N x 257 f32) -> fp16 table (stride 256, line-aligned rows)
//         + f32 psqt column; fc1_w (32x512 f32) -> fp16
// ---------------------------------------------------------------------------
__global__ __launch_bounds__(256) void convert_all(
    const float* __restrict__ ft_w, const float* __restrict__ fc1_w,
    _Float16* __restrict__ tbl, float* __restrict__ psq,
    _Float16* __restrict__ w1h, int n_fts)
{
    const int t0 = n_fts * HALF;
    const int t1 = t0 + n_fts;
    const int t2 = t1 + 32 * 2 * HALF;
    for (int i = blockIdx.x * 256 + threadIdx.x; i < t2; i += gridDim.x * 256) {
        if (i < t0) {
            int r = i >> 8, e = i & 255;
            tbl[i] = (_Float16)ft_w[r * ROWLEN + e];
        } else if (i < t1) {
            int r = i - t0;
            psq[r] = ft_w[r * ROWLEN + HALF];
        } else {
            int k = i - t1;
            w1h[k] = (_Float16)fc1_w[k];
        }
    }
}

// ---------------------------------------------------------------------------
// Main: one sample per WAVE. 4 waves/block, fully independent (no barriers).
// Lane l owns accumulator elements 4l..4l+3 in registers; each gather row is
// one wave-wide 8B/lane load. fp16 pk-add accumulate; FC1 via v_dot2_f32_f16.
// ---------------------------------------------------------------------------
__global__ __launch_bounds__(256) void nnue_wave(
    const int* __restrict__ wft, const int* __restrict__ bft,
    const float* __restrict__ stm,
    const _Float16* __restrict__ tbl, const float* __restrict__ psq,
    const _Float16* __restrict__ w1h,
    const float* __restrict__ ft_b,
    const float* __restrict__ fc1_b, const float* __restrict__ fc2_w,
    const float* __restrict__ fc2_b, const float* __restrict__ fco_w,
    const float* __restrict__ fco_b,
    float* __restrict__ out, int B)
{
    const int t  = threadIdx.x;
    const int wv = t >> 6;
    const int l  = t & 63;
    const int s  = (blockIdx.x << 2) + wv;

    __shared__ __attribute__((aligned(16))) _Float16 s_x[4][512];
    __shared__ float s_h1[4][32];

    if (s >= B) return;

    const int* wfts = wft + s * MAX_FTS;
    const int* bfts = bft + s * MAX_FTS;

    // ---- feature-transform gathers: 56 independent 8B/lane loads ----
    f16x4 aw = {(_Float16)0, (_Float16)0, (_Float16)0, (_Float16)0};
    f16x4 ab = {(_Float16)0, (_Float16)0, (_Float16)0, (_Float16)0};
    const _Float16* gbase = tbl + (l << 2);
#pragma unroll
    for (int i = 0; i < MAX_FTS; ++i) {
        const int icw = __builtin_amdgcn_readfirstlane(wfts[i]);
        if (icw >= 0) aw += *(const f16x4*)(gbase + ((long)icw << 8));
        const int icb = __builtin_amdgcn_readfirstlane(bfts[i]);
        if (icb >= 0) ab += *(const f16x4*)(gbase + ((long)icb << 8));
    }

    // ---- psqt diff (exact f32 path), butterfly across the wave ----
    float pv = 0.0f;
    if (l < MAX_FTS) {
        const int ic = wfts[l];
        if (ic >= 0) pv = psq[ic];
    } else if (l >= 32 && l < 32 + MAX_FTS) {
        const int ic = bfts[l - 32];
        if (ic >= 0) pv = -psq[ic];
    }
    pv += __shfl_xor(pv, 1, 64);
    pv += __shfl_xor(pv, 2, 64);
    pv += __shfl_xor(pv, 4, 64);
    pv += __shfl_xor(pv, 8, 64);
    pv += __shfl_xor(pv, 16, 64);
    pv += __shfl_xor(pv, 32, 64);

    // ---- + ft_b, stm lerp, clip, stage x (fp16) to wave-local LDS ----
    const f32x4 fb = *(const f32x4*)(ft_b + (l << 2));
    const float st = stm[s];
    const float os = 1.0f - st;
    f16x4 hxl, hxh;
#pragma unroll
    for (int k = 0; k < 4; ++k) {
        const float accw = (float)aw[k] + fb[k];
        const float accb = (float)ab[k] + fb[k];
        float xl = os * accw + st * accb;
        float xh = os * accb + st * accw;
        hxl[k] = (_Float16)fminf(fmaxf(xl, 0.0f), 1.0f);
        hxh[k] = (_Float16)fminf(fmaxf(xh, 0.0f), 1.0f);
    }
    *(f16x4*)(&s_x[wv][l << 2])        = hxl;
    *(f16x4*)(&s_x[wv][HALF + (l << 2)]) = hxh;
    __builtin_amdgcn_wave_barrier();
    asm volatile("" ::: "memory");

    // ---- FC1: lane (j = l&31, hf = l>>5) does 256 MACs via dot2 ----
    const int j  = l & 31;
    const int hf = l >> 5;
    const _Float16* w1p = w1h + (j << 9) + (hf << 8);
    const _Float16* xs  = &s_x[wv][hf << 8];
    float part = 0.0f;
#pragma unroll
    for (int i = 0; i < 32; ++i) {
        const f16x8 wv8 = *(const f16x8*)(w1p + (i << 3));
        const f16x8 xv8 = *(const f16x8*)(xs  + (i << 3));
#pragma unroll
        for (int k = 0; k < 4; ++k) {
            f16x2 a = {wv8[2 * k], wv8[2 * k + 1]};
            f16x2 b = {xv8[2 * k], xv8[2 * k + 1]};
#if __has_builtin(__builtin_amdgcn_fdot2)
            part = __builtin_amdgcn_fdot2(a, b, part, false);
#else
            part = fmaf((float)a[0], (float)b[0], part);
            part = fmaf((float)a[1], (float)b[1], part);
#endif
        }
    }
    part += __shfl_xor(part, 32, 64);
    const float h1 = fminf(fmaxf(part + fc1_b[j], 0.0f), 1.0f);
    if (l < 32) s_h1[wv][j] = h1;
    __builtin_amdgcn_wave_barrier();
    asm volatile("" ::: "memory");

    // ---- FC2 (duplicated across half-waves) ----
    float a2 = fc2_b[j];
    const float* w2 = fc2_w + (j << 5);
#pragma unroll
    for (int k = 0; k < 32; ++k) a2 = fmaf(s_h1[wv][k], w2[k], a2);
    const float h2 = fminf(fmaxf(a2, 0.0f), 1.0f);

    // ---- FCO: 32-lane butterfly dot ----
    float o = h2 * fco_w[j];
    o += __shfl_xor(o, 1, 64);
    o += __shfl_xor(o, 2, 64);
    o += __shfl_xor(o, 4, 64);
    o += __shfl_xor(o, 8, 64);
    o += __shfl_xor(o, 16, 64);
    if (l == 0) out[s] = o + fco_b[0] + pv * (0.5f - st);
}

// ---------------------------------------------------------------------------
// Fallback (verified R1 f32 kernel) — used only if ws is too small.
// ---------------------------------------------------------------------------
__global__ __launch_bounds__(256) void nnue_fwd(
    const int* __restrict__ wft, const int* __restrict__ bft,
    const float* __restrict__ stm, const float* __restrict__ ft_w,
    const float* __restrict__ ft_b, const float* __restrict__ fc1_w,
    const float* __restrict__ fc1_b, const float* __restrict__ fc2_w,
    const float* __restrict__ fc2_b, const float* __restrict__ fco_w,
    const float* __restrict__ fco_b, float* __restrict__ out)
{
    const int s = blockIdx.x;
    const int t = threadIdx.x;
    __shared__ int   s_iw[MAX_FTS];
    __shared__ int   s_ib[MAX_FTS];
    __shared__ float s_xx[2 * HALF];
    __shared__ float s_a[32];
    __shared__ float s_b[32];
    __shared__ float s_ps[2];

    if (t < MAX_FTS)                      s_iw[t]      = wft[s * MAX_FTS + t];
    else if (t >= 64 && t < 64 + MAX_FTS) s_ib[t - 64] = bft[s * MAX_FTS + (t - 64)];
    __syncthreads();

    float accw = ft_b[t];
    float accb = ft_b[t];
#pragma unroll
    for (int i = 0; i < MAX_FTS; ++i) {
        int icw = __builtin_amdgcn_readfirstlane(s_iw[i]);
        int icb = __builtin_amdgcn_readfirstlane(s_ib[i]);
        float mw = icw >= 0 ? 1.0f : 0.0f;
        float mb = icb >= 0 ? 1.0f : 0.0f;
        int ow = (icw >= 0 ? icw : 0) * ROWLEN;
        int ob = (icb >= 0 ? icb : 0) * ROWLEN;
        accw = fmaf(ft_w[ow + t], mw, accw);
        accb = fmaf(ft_w[ob + t], mb, accb);
    }
    if (t == 0 || t == 64) {
        const int* idx = (t == 0) ? s_iw : s_ib;
        float ps = 0.0f;
#pragma unroll
        for (int i = 0; i < MAX_FTS; ++i) {
            int ic = idx[i];
            float m = ic >= 0 ? 1.0f : 0.0f;
            int o = (ic >= 0 ? ic : 0) * ROWLEN;
            ps = fmaf(ft_w[o + HALF], m, ps);
        }
        s_ps[t == 0 ? 0 : 1] = ps;
    }
    const float st = stm[s];
    float xl = (1.0f - st) * accw + st * accb;
    float xh = (1.0f - st) * accb + st * accw;
    s_xx[t]        = fminf(fmaxf(xl, 0.0f), 1.0f);
    s_xx[t + HALF] = fminf(fmaxf(xh, 0.0f), 1.0f);
    __syncthreads();

    const int j = t >> 3, p = t & 7;
    const float* w1 = fc1_w + j * (2 * HALF);
    float part = 0.0f;
#pragma unroll
    for (int i = 0; i < 64; ++i) {
        int k = (i << 3) | p;
        part = fmaf(s_xx[k], w1[k], part);
    }
    part += __shfl_xor(part, 1, 64);
    part += __shfl_xor(part, 2, 64);
    part += __shfl_xor(part, 4, 64);
    if (p == 0) s_a[j] = fminf(fmaxf(part + fc1_b[j], 0.0f), 1.0f);
    __syncthreads();

    if (t < 32) {
        float a = fc2_b[t];
        const float* w2 = fc2_w + t * 32;
#pragma unroll
        for (int k = 0; k < 32; ++k) a = fmaf(s_a[k], w2[k], a);
        s_b[t] = fminf(fmaxf(a, 0.0f), 1.0f);
    }
    __syncthreads();

    if (t == 0) {
        float o = fco_b[0];
#pragma unroll
        for (int k = 0; k < 32; ++k) o = fmaf(s_b[k], fco_w[k], o);
        o += (s_ps[0] - s_ps[1]) * (0.5f - st);
        out[s] = o;
    }
}

extern "C" void kernel_launch(void* const* d_in, const int* in_sizes, int n_in,
                              void* d_out, int out_size, void* d_ws, size_t ws_size,
                              hipStream_t stream) {
    const int*   wft   = (const int*)  d_in[0];
    const int*   bft   = (const int*)  d_in[1];
    const float* stm   = (const float*)d_in[2];
    const float* ft_w  = (const float*)d_in[3];
    const float* ft_b  = (const float*)d_in[4];
    const float* fc1_w = (const float*)d_in[5];
    const float* fc1_b = (const float*)d_in[6];
    const float* fc2_w = (const float*)d_in[7];
    const float* fc2_b = (const float*)d_in[8];
    const float* fco_w = (const float*)d_in[9];
    const float* fco_b = (const float*)d_in[10];
    float* out = (float*)d_out;

    const int B     = in_sizes[0] / MAX_FTS;
    const int n_fts = in_sizes[3] / ROWLEN;

    const size_t psq_bytes = (size_t)n_fts * sizeof(float);       // 16B-multiple
    const size_t w1h_bytes = (size_t)32 * 2 * HALF * sizeof(_Float16);
    const size_t tbl_bytes = (size_t)n_fts * HALF * sizeof(_Float16);
    const size_t need = psq_bytes + w1h_bytes + tbl_bytes;

    if (ws_size >= need) {
        float*    psq = (float*)d_ws;
        _Float16* w1h = (_Float16*)((char*)d_ws + psq_bytes);
        _Float16* tbl = (_Float16*)((char*)d_ws + psq_bytes + w1h_bytes);
        convert_all<<<4096, 256, 0, stream>>>(ft_w, fc1_w, tbl, psq, w1h, n_fts);
        nnue_wave<<<(B + 3) / 4, 256, 0, stream>>>(wft, bft, stm, tbl, psq, w1h,
                                                   ft_b, fc1_b, fc2_w, fc2_b,
                                                   fco_w, fco_b, out, B);
    } else {
        nnue_fwd<<<B, 256, 0, stream>>>(wft, bft, stm, ft_w, ft_b,
                                        fc1_w, fc1_b, fc2_w, fc2_b,
                                        fco_w, fco_b, out);
    }
}

// Round 4
// 136.927 us; speedup vs baseline: 1.1975x; 1.1975x over previous
//
#include <hip/hip_runtime.h>

#define MAX_FTS 30
#define HALF 256
#define ROWLEN 257

typedef __attribute__((ext_vector_type(2))) _Float16 f16x2;
typedef __attribute__((ext_vector_type(4))) _Float16 f16x4;
typedef __attribute__((ext_vector_type(8))) _Float16 f16x8;
typedef __attribute__((ext_vector_type(4))) float    f32x4;

// ---------------------------------------------------------------------------
// Pass 0: ft_w (N x 257 f32) -> fp16 table (stride 256) + zero row at index N
//         + f32 psqt column (with psq[N] = 0); fc1_w (32x512 f32) -> fp16
// ---------------------------------------------------------------------------
__global__ __launch_bounds__(256) void convert_all(
    const float* __restrict__ ft_w, const float* __restrict__ fc1_w,
    _Float16* __restrict__ tbl, float* __restrict__ psq,
    _Float16* __restrict__ w1h, int n_fts)
{
    const int t0 = n_fts * HALF;          // tbl body
    const int t1 = t0 + n_fts;            // psq column
    const int t2 = t1 + 32 * 2 * HALF;    // fc1 weights
    const int t3 = t2 + HALF + 1;         // zero row + psq zero
    for (int i = blockIdx.x * 256 + threadIdx.x; i < t3; i += gridDim.x * 256) {
        if (i < t0) {
            int r = i >> 8, e = i & 255;
            tbl[i] = (_Float16)ft_w[r * ROWLEN + e];
        } else if (i < t1) {
            int r = i - t0;
            psq[r] = ft_w[r * ROWLEN + HALF];
        } else if (i < t2) {
            int k = i - t1;
            w1h[k] = (_Float16)fc1_w[k];
        } else if (i < t2 + HALF) {
            tbl[(size_t)n_fts * HALF + (i - t2)] = (_Float16)0;
        } else {
            psq[n_fts] = 0.0f;
        }
    }
}

// ---------------------------------------------------------------------------
// Main: one sample per WAVE, no block barriers, branch-free gather loop.
// Indices prefetched into lane registers (one vmcnt wait), extracted with
// readlane to SGPRs; invalid rows redirect to the zero row. 60 independent
// 8B/lane row-gathers stream through the vmcnt queue.
// ---------------------------------------------------------------------------
__global__ __launch_bounds__(256) void nnue_wave(
    const int* __restrict__ wft, const int* __restrict__ bft,
    const float* __restrict__ stm,
    const _Float16* __restrict__ tbl, const float* __restrict__ psq,
    const _Float16* __restrict__ w1h,
    const float* __restrict__ ft_b,
    const float* __restrict__ fc1_b, const float* __restrict__ fc2_w,
    const float* __restrict__ fc2_b, const float* __restrict__ fco_w,
    const float* __restrict__ fco_b,
    float* __restrict__ out, int B, int zr)
{
    const int t  = threadIdx.x;
    const int wv = t >> 6;
    const int l  = t & 63;
    const int s  = (blockIdx.x << 2) + wv;

    __shared__ __attribute__((aligned(16))) _Float16 s_x[4][512];

    if (s >= B) return;

    // ---- index prefetch: 2 vector loads, lanes 0..29 hold the real indices ----
    const int lc = (l < MAX_FTS) ? l : (MAX_FTS - 1);
    const int iwv = wft[s * MAX_FTS + lc];
    const int ibv = bft[s * MAX_FTS + lc];

    // ---- 60 unconditional row gathers (invalid -> zero row) ----
    f16x4 aw = {(_Float16)0, (_Float16)0, (_Float16)0, (_Float16)0};
    f16x4 ab = {(_Float16)0, (_Float16)0, (_Float16)0, (_Float16)0};
    const _Float16* gb = tbl + (l << 2);
#pragma unroll
    for (int i = 0; i < MAX_FTS; ++i) {
        int icw = __builtin_amdgcn_readlane(iwv, i);
        icw = (icw < 0) ? zr : icw;
        aw += *(const f16x4*)(gb + ((long)icw << 8));
        int icb = __builtin_amdgcn_readlane(ibv, i);
        icb = (icb < 0) ? zr : icb;
        ab += *(const f16x4*)(gb + ((long)icb << 8));
    }

    // ---- psqt diff (exact f32), clamped-index loads, butterfly sum ----
    float pv = 0.0f;
    if (l < MAX_FTS) {
        const int cw = (iwv < 0) ? zr : iwv;
        const int cb = (ibv < 0) ? zr : ibv;
        pv = psq[cw] - psq[cb];
    }
    pv += __shfl_xor(pv, 1, 64);
    pv += __shfl_xor(pv, 2, 64);
    pv += __shfl_xor(pv, 4, 64);
    pv += __shfl_xor(pv, 8, 64);
    pv += __shfl_xor(pv, 16, 64);
    pv += __shfl_xor(pv, 32, 64);

    // ---- + ft_b, stm lerp, clip, stage x (fp16) to wave-local LDS ----
    const f32x4 fb = *(const f32x4*)(ft_b + (l << 2));
    const float st = stm[s];
    const float os = 1.0f - st;
    f16x4 hxl, hxh;
#pragma unroll
    for (int k = 0; k < 4; ++k) {
        const float accw = (float)aw[k] + fb[k];
        const float accb = (float)ab[k] + fb[k];
        float xl = os * accw + st * accb;
        float xh = os * accb + st * accw;
        hxl[k] = (_Float16)fminf(fmaxf(xl, 0.0f), 1.0f);
        hxh[k] = (_Float16)fminf(fmaxf(xh, 0.0f), 1.0f);
    }
    *(f16x4*)(&s_x[wv][l << 2])          = hxl;
    *(f16x4*)(&s_x[wv][HALF + (l << 2)]) = hxh;
    __builtin_amdgcn_wave_barrier();
    asm volatile("" ::: "memory");

    // ---- FC1: lane (j=l&31, hf=l>>5) does 256 MACs via dot2, 4 acc chains ----
    const int j  = l & 31;
    const int hf = l >> 5;
    const _Float16* w1p = w1h + (j << 9) + (hf << 8);
    const _Float16* xs  = &s_x[wv][hf << 8];
    float acc0 = 0.0f, acc1 = 0.0f, acc2 = 0.0f, acc3 = 0.0f;
#pragma unroll
    for (int i = 0; i < 32; ++i) {
        const f16x8 wv8 = *(const f16x8*)(w1p + (i << 3));
        const f16x8 xv8 = *(const f16x8*)(xs  + (i << 3));
        f16x2 a0 = {wv8[0], wv8[1]}, b0 = {xv8[0], xv8[1]};
        f16x2 a1 = {wv8[2], wv8[3]}, b1 = {xv8[2], xv8[3]};
        f16x2 a2 = {wv8[4], wv8[5]}, b2 = {xv8[4], xv8[5]};
        f16x2 a3 = {wv8[6], wv8[7]}, b3 = {xv8[6], xv8[7]};
#if __has_builtin(__builtin_amdgcn_fdot2)
        acc0 = __builtin_amdgcn_fdot2(a0, b0, acc0, false);
        acc1 = __builtin_amdgcn_fdot2(a1, b1, acc1, false);
        acc2 = __builtin_amdgcn_fdot2(a2, b2, acc2, false);
        acc3 = __builtin_amdgcn_fdot2(a3, b3, acc3, false);
#else
        acc0 = fmaf((float)a0[0], (float)b0[0], fmaf((float)a0[1], (float)b0[1], acc0));
        acc1 = fmaf((float)a1[0], (float)b1[0], fmaf((float)a1[1], (float)b1[1], acc1));
        acc2 = fmaf((float)a2[0], (float)b2[0], fmaf((float)a2[1], (float)b2[1], acc2));
        acc3 = fmaf((float)a3[0], (float)b3[0], fmaf((float)a3[1], (float)b3[1], acc3));
#endif
    }
    float part = (acc0 + acc1) + (acc2 + acc3);
    part += __shfl_xor(part, 32, 64);
    const float h1 = fminf(fmaxf(part + fc1_b[j], 0.0f), 1.0f);

    __shared__ float s_h1[4][32];
    if (l < 32) s_h1[wv][j] = h1;
    __builtin_amdgcn_wave_barrier();
    asm volatile("" ::: "memory");

    // ---- FC2 (duplicated across half-waves) ----
    float a2v = fc2_b[j];
    const float* w2 = fc2_w + (j << 5);
#pragma unroll
    for (int k = 0; k < 32; ++k) a2v = fmaf(s_h1[wv][k], w2[k], a2v);
    const float h2 = fminf(fmaxf(a2v, 0.0f), 1.0f);

    // ---- FCO: 32-lane butterfly dot ----
    float o = h2 * fco_w[j];
    o += __shfl_xor(o, 1, 64);
    o += __shfl_xor(o, 2, 64);
    o += __shfl_xor(o, 4, 64);
    o += __shfl_xor(o, 8, 64);
    o += __shfl_xor(o, 16, 64);
    if (l == 0) out[s] = o + fco_b[0] + pv * (0.5f - st);
}

// ---------------------------------------------------------------------------
// Fallback (verified R1 f32 kernel) — used only if ws is too small.
// ---------------------------------------------------------------------------
__global__ __launch_bounds__(256) void nnue_fwd(
    const int* __restrict__ wft, const int* __restrict__ bft,
    const float* __restrict__ stm, const float* __restrict__ ft_w,
    const float* __restrict__ ft_b, const float* __restrict__ fc1_w,
    const float* __restrict__ fc1_b, const float* __restrict__ fc2_w,
    const float* __restrict__ fc2_b, const float* __restrict__ fco_w,
    const float* __restrict__ fco_b, float* __restrict__ out)
{
    const int s = blockIdx.x;
    const int t = threadIdx.x;
    __shared__ int   s_iw[MAX_FTS];
    __shared__ int   s_ib[MAX_FTS];
    __shared__ float s_xx[2 * HALF];
    __shared__ float s_a[32];
    __shared__ float s_b[32];
    __shared__ float s_ps[2];

    if (t < MAX_FTS)                      s_iw[t]      = wft[s * MAX_FTS + t];
    else if (t >= 64 && t < 64 + MAX_FTS) s_ib[t - 64] = bft[s * MAX_FTS + (t - 64)];
    __syncthreads();

    float accw = ft_b[t];
    float accb = ft_b[t];
#pragma unroll
    for (int i = 0; i < MAX_FTS; ++i) {
        int icw = __builtin_amdgcn_readfirstlane(s_iw[i]);
        int icb = __builtin_amdgcn_readfirstlane(s_ib[i]);
        float mw = icw >= 0 ? 1.0f : 0.0f;
        float mb = icb >= 0 ? 1.0f : 0.0f;
        int ow = (icw >= 0 ? icw : 0) * ROWLEN;
        int ob = (icb >= 0 ? icb : 0) * ROWLEN;
        accw = fmaf(ft_w[ow + t], mw, accw);
        accb = fmaf(ft_w[ob + t], mb, accb);
    }
    if (t == 0 || t == 64) {
        const int* idx = (t == 0) ? s_iw : s_ib;
        float ps = 0.0f;
#pragma unroll
        for (int i = 0; i < MAX_FTS; ++i) {
            int ic = idx[i];
            float m = ic >= 0 ? 1.0f : 0.0f;
            int o = (ic >= 0 ? ic : 0) * ROWLEN;
            ps = fmaf(ft_w[o + HALF], m, ps);
        }
        s_ps[t == 0 ? 0 : 1] = ps;
    }
    const float st = stm[s];
    float xl = (1.0f - st) * accw + st * accb;
    float xh = (1.0f - st) * accb + st * accw;
    s_xx[t]        = fminf(fmaxf(xl, 0.0f), 1.0f);
    s_xx[t + HALF] = fminf(fmaxf(xh, 0.0f), 1.0f);
    __syncthreads();

    const int j = t >> 3, p = t & 7;
    const float* w1 = fc1_w + j * (2 * HALF);
    float part = 0.0f;
#pragma unroll
    for (int i = 0; i < 64; ++i) {
        int k = (i << 3) | p;
        part = fmaf(s_xx[k], w1[k], part);
    }
    part += __shfl_xor(part, 1, 64);
    part += __shfl_xor(part, 2, 64);
    part += __shfl_xor(part, 4, 64);
    if (p == 0) s_a[j] = fminf(fmaxf(part + fc1_b[j], 0.0f), 1.0f);
    __syncthreads();

    if (t < 32) {
        float a = fc2_b[t];
        const float* w2 = fc2_w + t * 32;
#pragma unroll
        for (int k = 0; k < 32; ++k) a = fmaf(s_a[k], w2[k], a);
        s_b[t] = fminf(fmaxf(a, 0.0f), 1.0f);
    }
    __syncthreads();

    if (t == 0) {
        float o = fco_b[0];
#pragma unroll
        for (int k = 0; k < 32; ++k) o = fmaf(s_b[k], fco_w[k], o);
        o += (s_ps[0] - s_ps[1]) * (0.5f - st);
        out[s] = o;
    }
}

extern "C" void kernel_launch(void* const* d_in, const int* in_sizes, int n_in,
                              void* d_out, int out_size, void* d_ws, size_t ws_size,
                              hipStream_t stream) {
    const int*   wft   = (const int*)  d_in[0];
    const int*   bft   = (const int*)  d_in[1];
    const float* stm   = (const float*)d_in[2];
    const float* ft_w  = (const float*)d_in[3];
    const float* ft_b  = (const float*)d_in[4];
    const float* fc1_w = (const float*)d_in[5];
    const float* fc1_b = (const float*)d_in[6];
    const float* fc2_w = (const float*)d_in[7];
    const float* fc2_b = (const float*)d_in[8];
    const float* fco_w = (const float*)d_in[9];
    const float* fco_b = (const float*)d_in[10];
    float* out = (float*)d_out;

    const int B     = in_sizes[0] / MAX_FTS;
    const int n_fts = in_sizes[3] / ROWLEN;

    const size_t psq_bytes = (((size_t)(n_fts + 1) * sizeof(float)) + 15) & ~(size_t)15;
    const size_t w1h_bytes = (size_t)32 * 2 * HALF * sizeof(_Float16);
    const size_t tbl_bytes = (size_t)(n_fts + 1) * HALF * sizeof(_Float16);
    const size_t need = psq_bytes + w1h_bytes + tbl_bytes;

    if (ws_size >= need) {
        float*    psq = (float*)d_ws;
        _Float16* w1h = (_Float16*)((char*)d_ws + psq_bytes);
        _Float16* tbl = (_Float16*)((char*)d_ws + psq_bytes + w1h_bytes);
        convert_all<<<4096, 256, 0, stream>>>(ft_w, fc1_w, tbl, psq, w1h, n_fts);
        nnue_wave<<<(B + 3) / 4, 256, 0, stream>>>(wft, bft, stm, tbl, psq, w1h,
                                                   ft_b, fc1_b, fc2_w, fc2_b,
                                                   fco_w, fco_b, out, B, n_fts);
    } else {
        nnue_fwd<<<B, 256, 0, stream>>>(wft, bft, stm, ft_w, ft_b,
                                        fc1_w, fc1_b, fc2_w, fc2_b,
                                        fco_w, fco_b, out);
    }
}

// Round 5
// 118.807 us; speedup vs baseline: 1.3802x; 1.1525x over previous
//
#include <hip/hip_runtime.h>

#define MAX_FTS 30
#define HALF 256
#define ROWLEN 257

typedef __attribute__((ext_vector_type(2))) _Float16 f16x2;
typedef __attribute__((ext_vector_type(4))) _Float16 f16x4;
typedef __attribute__((ext_vector_type(8))) _Float16 f16x8;
typedef __attribute__((ext_vector_type(4))) float    f32x4;

// ---------------------------------------------------------------------------
// Pass 0a: per-row int8 quantization of ft_w fts columns (biased uint8,
// per-row f32 scale), one wave per row; also extracts the f32 psqt column.
// ---------------------------------------------------------------------------
__global__ __launch_bounds__(256) void quant_rows(
    const float* __restrict__ ft_w,
    unsigned char* __restrict__ tbl8,
    float* __restrict__ scl, float* __restrict__ psq, int n_fts)
{
    const int wv = threadIdx.x >> 6, l = threadIdx.x & 63;
    const int r = blockIdx.x * 4 + wv;
    if (r >= n_fts) return;
    const float* row = ft_w + (size_t)r * ROWLEN;

    float v[4];
#pragma unroll
    for (int k = 0; k < 4; ++k) v[k] = row[(l << 2) + k];

    float m = fmaxf(fmaxf(fabsf(v[0]), fabsf(v[1])), fmaxf(fabsf(v[2]), fabsf(v[3])));
#pragma unroll
    for (int d = 1; d < 64; d <<= 1) m = fmaxf(m, __shfl_xor(m, d, 64));

    const float s   = m * (1.0f / 127.0f);
    const float inv = (m > 0.0f) ? (127.0f / m) : 0.0f;

    unsigned int u = 0;
#pragma unroll
    for (int k = 0; k < 4; ++k) {
        int q = (int)rintf(v[k] * inv) + 128;
        u |= ((unsigned int)q & 0xffu) << (8 * k);
    }
    *(unsigned int*)(tbl8 + (size_t)r * 256 + (l << 2)) = u;
    if (l == 0) { scl[r] = s; psq[r] = row[HALF]; }
}

// ---------------------------------------------------------------------------
// Pass 0b: fc1_w -> fp16; zero row (biased 0x80) at index n_fts; zero scale/psq.
// ---------------------------------------------------------------------------
__global__ __launch_bounds__(256) void convert_misc(
    const float* __restrict__ fc1_w, _Float16* __restrict__ w1h,
    unsigned char* __restrict__ tbl8, float* __restrict__ scl,
    float* __restrict__ psq, int n_fts)
{
    const int i = blockIdx.x * 256 + threadIdx.x;
    if (i < 32 * 2 * HALF) w1h[i] = (_Float16)fc1_w[i];
    if (blockIdx.x == 0) {
        if (threadIdx.x < 64)
            ((unsigned int*)(tbl8 + (size_t)n_fts * 256))[threadIdx.x] = 0x80808080u;
        if (threadIdx.x == 64) { scl[n_fts] = 0.0f; psq[n_fts] = 0.0f; }
    }
}

// ---------------------------------------------------------------------------
// Main: one sample per WAVE, branch-free int8 gather loop. Indices and
// per-row scales prefetched into lane registers (vector loads), extracted
// with readlane; invalid rows redirect to the zero row (scale 0).
// acc = sum(s_i * u_ik) - 128*sum(s_i), exact dequant in f32.
// ---------------------------------------------------------------------------
__global__ __launch_bounds__(256) void nnue_wave(
    const int* __restrict__ wft, const int* __restrict__ bft,
    const float* __restrict__ stm,
    const unsigned char* __restrict__ tbl8, const float* __restrict__ scl,
    const float* __restrict__ psq, const _Float16* __restrict__ w1h,
    const float* __restrict__ ft_b,
    const float* __restrict__ fc1_b, const float* __restrict__ fc2_w,
    const float* __restrict__ fc2_b, const float* __restrict__ fco_w,
    const float* __restrict__ fco_b,
    float* __restrict__ out, int B, int zr)
{
    const int t  = threadIdx.x;
    const int wv = t >> 6;
    const int l  = t & 63;
    const int s  = (blockIdx.x << 2) + wv;

    __shared__ __attribute__((aligned(16))) _Float16 s_x[4][512];
    __shared__ float s_h1[4][32];

    if (s >= B) return;

    // ---- prefetch indices + per-row scales + psqt into lane registers ----
    const int lc  = (l < MAX_FTS) ? l : (MAX_FTS - 1);
    const int iwv = wft[s * MAX_FTS + lc];
    const int ibv = bft[s * MAX_FTS + lc];
    const int cwl = (iwv < 0) ? zr : iwv;
    const int cbl = (ibv < 0) ? zr : ibv;

    float swv_ = 0.0f, sbv_ = 0.0f, pv = 0.0f;
    if (l < MAX_FTS) {
        swv_ = scl[cwl];
        sbv_ = scl[cbl];
        pv   = psq[cwl] - psq[cbl];
    }

    // ---- 60 unconditional int8 row gathers (4B/lane, 256B/row) ----
    f32x4 aw = {0.0f, 0.0f, 0.0f, 0.0f};
    f32x4 ab = {0.0f, 0.0f, 0.0f, 0.0f};
    const unsigned char* gb = tbl8 + (l << 2);
    const int swv_i = __builtin_bit_cast(int, swv_);
    const int sbv_i = __builtin_bit_cast(int, sbv_);
#pragma unroll
    for (int i = 0; i < MAX_FTS; ++i) {
        int icw = __builtin_amdgcn_readlane(iwv, i);
        icw = (icw < 0) ? zr : icw;
        const unsigned int qw = *(const unsigned int*)(gb + ((size_t)icw << 8));
        const float sw = __builtin_bit_cast(float, __builtin_amdgcn_readlane(swv_i, i));
        aw[0] = fmaf(sw, (float)( qw        & 0xffu), aw[0]);
        aw[1] = fmaf(sw, (float)((qw >>  8) & 0xffu), aw[1]);
        aw[2] = fmaf(sw, (float)((qw >> 16) & 0xffu), aw[2]);
        aw[3] = fmaf(sw, (float)( qw >> 24        ), aw[3]);

        int icb = __builtin_amdgcn_readlane(ibv, i);
        icb = (icb < 0) ? zr : icb;
        const unsigned int qb = *(const unsigned int*)(gb + ((size_t)icb << 8));
        const float sb = __builtin_bit_cast(float, __builtin_amdgcn_readlane(sbv_i, i));
        ab[0] = fmaf(sb, (float)( qb        & 0xffu), ab[0]);
        ab[1] = fmaf(sb, (float)((qb >>  8) & 0xffu), ab[1]);
        ab[2] = fmaf(sb, (float)((qb >> 16) & 0xffu), ab[2]);
        ab[3] = fmaf(sb, (float)( qb >> 24        ), ab[3]);
    }

    // ---- scale sums (for the +128 bias removal) + psqt diff, butterflies ----
    float ssw = swv_, ssb = sbv_;
#pragma unroll
    for (int d = 1; d < 64; d <<= 1) {
        ssw += __shfl_xor(ssw, d, 64);
        ssb += __shfl_xor(ssb, d, 64);
        pv  += __shfl_xor(pv,  d, 64);
    }

    // ---- + ft_b, stm lerp, clip, stage x (fp16) to wave-local LDS ----
    const f32x4 fb = *(const f32x4*)(ft_b + (l << 2));
    const float st = stm[s];
    const float os = 1.0f - st;
    const float bw = 128.0f * ssw;
    const float bb = 128.0f * ssb;
    f16x4 hxl, hxh;
#pragma unroll
    for (int k = 0; k < 4; ++k) {
        const float accw = (aw[k] - bw) + fb[k];
        const float accb = (ab[k] - bb) + fb[k];
        float xl = os * accw + st * accb;
        float xh = os * accb + st * accw;
        hxl[k] = (_Float16)fminf(fmaxf(xl, 0.0f), 1.0f);
        hxh[k] = (_Float16)fminf(fmaxf(xh, 0.0f), 1.0f);
    }
    *(f16x4*)(&s_x[wv][l << 2])          = hxl;
    *(f16x4*)(&s_x[wv][HALF + (l << 2)]) = hxh;
    __builtin_amdgcn_wave_barrier();
    asm volatile("" ::: "memory");

    // ---- FC1: lane (j=l&31, hf=l>>5) does 256 MACs via dot2, 4 acc chains ----
    const int j  = l & 31;
    const int hf = l >> 5;
    const _Float16* w1p = w1h + (j << 9) + (hf << 8);
    const _Float16* xs  = &s_x[wv][hf << 8];
    float acc0 = 0.0f, acc1 = 0.0f, acc2 = 0.0f, acc3 = 0.0f;
#pragma unroll
    for (int i = 0; i < 32; ++i) {
        const f16x8 wv8 = *(const f16x8*)(w1p + (i << 3));
        const f16x8 xv8 = *(const f16x8*)(xs  + (i << 3));
        f16x2 a0 = {wv8[0], wv8[1]}, b0 = {xv8[0], xv8[1]};
        f16x2 a1 = {wv8[2], wv8[3]}, b1 = {xv8[2], xv8[3]};
        f16x2 a2 = {wv8[4], wv8[5]}, b2 = {xv8[4], xv8[5]};
        f16x2 a3 = {wv8[6], wv8[7]}, b3 = {xv8[6], xv8[7]};
#if __has_builtin(__builtin_amdgcn_fdot2)
        acc0 = __builtin_amdgcn_fdot2(a0, b0, acc0, false);
        acc1 = __builtin_amdgcn_fdot2(a1, b1, acc1, false);
        acc2 = __builtin_amdgcn_fdot2(a2, b2, acc2, false);
        acc3 = __builtin_amdgcn_fdot2(a3, b3, acc3, false);
#else
        acc0 = fmaf((float)a0[0], (float)b0[0], fmaf((float)a0[1], (float)b0[1], acc0));
        acc1 = fmaf((float)a1[0], (float)b1[0], fmaf((float)a1[1], (float)b1[1], acc1));
        acc2 = fmaf((float)a2[0], (float)b2[0], fmaf((float)a2[1], (float)b2[1], acc2));
        acc3 = fmaf((float)a3[0], (float)b3[0], fmaf((float)a3[1], (float)b3[1], acc3));
#endif
    }
    float part = (acc0 + acc1) + (acc2 + acc3);
    part += __shfl_xor(part, 32, 64);
    const float h1 = fminf(fmaxf(part + fc1_b[j], 0.0f), 1.0f);
    if (l < 32) s_h1[wv][j] = h1;
    __builtin_amdgcn_wave_barrier();
    asm volatile("" ::: "memory");

    // ---- FC2 (duplicated across half-waves) ----
    float a2v = fc2_b[j];
    const float* w2 = fc2_w + (j << 5);
#pragma unroll
    for (int k = 0; k < 32; ++k) a2v = fmaf(s_h1[wv][k], w2[k], a2v);
    const float h2 = fminf(fmaxf(a2v, 0.0f), 1.0f);

    // ---- FCO: 32-lane butterfly dot ----
    float o = h2 * fco_w[j];
    o += __shfl_xor(o, 1, 64);
    o += __shfl_xor(o, 2, 64);
    o += __shfl_xor(o, 4, 64);
    o += __shfl_xor(o, 8, 64);
    o += __shfl_xor(o, 16, 64);
    if (l == 0) out[s] = o + fco_b[0] + pv * (0.5f - st);
}

// ---------------------------------------------------------------------------
// Fallback (verified R1 f32 kernel) — used only if ws is too small.
// ---------------------------------------------------------------------------
__global__ __launch_bounds__(256) void nnue_fwd(
    const int* __restrict__ wft, const int* __restrict__ bft,
    const float* __restrict__ stm, const float* __restrict__ ft_w,
    const float* __restrict__ ft_b, const float* __restrict__ fc1_w,
    const float* __restrict__ fc1_b, const float* __restrict__ fc2_w,
    const float* __restrict__ fc2_b, const float* __restrict__ fco_w,
    const float* __restrict__ fco_b, float* __restrict__ out)
{
    const int s = blockIdx.x;
    const int t = threadIdx.x;
    __shared__ int   s_iw[MAX_FTS];
    __shared__ int   s_ib[MAX_FTS];
    __shared__ float s_xx[2 * HALF];
    __shared__ float s_a[32];
    __shared__ float s_b[32];
    __shared__ float s_ps[2];

    if (t < MAX_FTS)                      s_iw[t]      = wft[s * MAX_FTS + t];
    else if (t >= 64 && t < 64 + MAX_FTS) s_ib[t - 64] = bft[s * MAX_FTS + (t - 64)];
    __syncthreads();

    float accw = ft_b[t];
    float accb = ft_b[t];
#pragma unroll
    for (int i = 0; i < MAX_FTS; ++i) {
        int icw = __builtin_amdgcn_readfirstlane(s_iw[i]);
        int icb = __builtin_amdgcn_readfirstlane(s_ib[i]);
        float mw = icw >= 0 ? 1.0f : 0.0f;
        float mb = icb >= 0 ? 1.0f : 0.0f;
        int ow = (icw >= 0 ? icw : 0) * ROWLEN;
        int ob = (icb >= 0 ? icb : 0) * ROWLEN;
        accw = fmaf(ft_w[ow + t], mw, accw);
        accb = fmaf(ft_w[ob + t], mb, accb);
    }
    if (t == 0 || t == 64) {
        const int* idx = (t == 0) ? s_iw : s_ib;
        float ps = 0.0f;
#pragma unroll
        for (int i = 0; i < MAX_FTS; ++i) {
            int ic = idx[i];
            float m = ic >= 0 ? 1.0f : 0.0f;
            int o = (ic >= 0 ? ic : 0) * ROWLEN;
            ps = fmaf(ft_w[o + HALF], m, ps);
        }
        s_ps[t == 0 ? 0 : 1] = ps;
    }
    const float st = stm[s];
    float xl = (1.0f - st) * accw + st * accb;
    float xh = (1.0f - st) * accb + st * accw;
    s_xx[t]        = fminf(fmaxf(xl, 0.0f), 1.0f);
    s_xx[t + HALF] = fminf(fmaxf(xh, 0.0f), 1.0f);
    __syncthreads();

    const int j = t >> 3, p = t & 7;
    const float* w1 = fc1_w + j * (2 * HALF);
    float part = 0.0f;
#pragma unroll
    for (int i = 0; i < 64; ++i) {
        int k = (i << 3) | p;
        part = fmaf(s_xx[k], w1[k], part);
    }
    part += __shfl_xor(part, 1, 64);
    part += __shfl_xor(part, 2, 64);
    part += __shfl_xor(part, 4, 64);
    if (p == 0) s_a[j] = fminf(fmaxf(part + fc1_b[j], 0.0f), 1.0f);
    __syncthreads();

    if (t < 32) {
        float a = fc2_b[t];
        const float* w2 = fc2_w + t * 32;
#pragma unroll
        for (int k = 0; k < 32; ++k) a = fmaf(s_a[k], w2[k], a);
        s_b[t] = fminf(fmaxf(a, 0.0f), 1.0f);
    }
    __syncthreads();

    if (t == 0) {
        float o = fco_b[0];
#pragma unroll
        for (int k = 0; k < 32; ++k) o = fmaf(s_b[k], fco_w[k], o);
        o += (s_ps[0] - s_ps[1]) * (0.5f - st);
        out[s] = o;
    }
}

extern "C" void kernel_launch(void* const* d_in, const int* in_sizes, int n_in,
                              void* d_out, int out_size, void* d_ws, size_t ws_size,
                              hipStream_t stream) {
    const int*   wft   = (const int*)  d_in[0];
    const int*   bft   = (const int*)  d_in[1];
    const float* stm   = (const float*)d_in[2];
    const float* ft_w  = (const float*)d_in[3];
    const float* ft_b  = (const float*)d_in[4];
    const float* fc1_w = (const float*)d_in[5];
    const float* fc1_b = (const float*)d_in[6];
    const float* fc2_w = (const float*)d_in[7];
    const float* fc2_b = (const float*)d_in[8];
    const float* fco_w = (const float*)d_in[9];
    const float* fco_b = (const float*)d_in[10];
    float* out = (float*)d_out;

    const int B     = in_sizes[0] / MAX_FTS;
    const int n_fts = in_sizes[3] / ROWLEN;

    const size_t colpad    = (((size_t)(n_fts + 1) * sizeof(float)) + 15) & ~(size_t)15;
    const size_t w1h_bytes = (size_t)32 * 2 * HALF * sizeof(_Float16);
    const size_t tbl_bytes = (size_t)(n_fts + 1) * 256;
    const size_t need = 2 * colpad + w1h_bytes + tbl_bytes;

    if (ws_size >= need) {
        float*         scl  = (float*)d_ws;
        float*         psq  = (float*)((char*)d_ws + colpad);
        _Float16*      w1h  = (_Float16*)((char*)d_ws + 2 * colpad);
        unsigned char* tbl8 = (unsigned char*)((char*)d_ws + 2 * colpad + w1h_bytes);

        quant_rows<<<(n_fts + 3) / 4, 256, 0, stream>>>(ft_w, tbl8, scl, psq, n_fts);
        convert_misc<<<64, 256, 0, stream>>>(fc1_w, w1h, tbl8, scl, psq, n_fts);
        nnue_wave<<<(B + 3) / 4, 256, 0, stream>>>(wft, bft, stm, tbl8, scl, psq,
                                                   w1h, ft_b, fc1_b, fc2_w, fc2_b,
                                                   fco_w, fco_b, out, B, n_fts);
    } else {
        nnue_fwd<<<B, 256, 0, stream>>>(wft, bft, stm, ft_w, ft_b,
                                        fc1_w, fc1_b, fc2_w, fc2_b,
                                        fco_w, fco_b, out);
    }
}